// Round 4
// baseline (957.333 us; speedup 1.0000x reference)
//
#include <hip/hip_runtime.h>
#include <hip/hip_bf16.h>
#include <cstdint>

// ---------------------------------------------------------------------------
// RecurrentResourceActionHead — fused single-pass implementation.
//
// Key algebra:
//  * x = [main_inputs, output]; x@W1 = main@W1[0:256] (iteration-invariant,
//    computed ONCE) + counts@W1[256:262] (rank<=5 correction per iteration).
//  * h is unobserved: logits = relu(LN)@(W2@Wd) + (b2@Wd + bd). W2@Wd (128x6)
//    precomputed by prep_kernel -> kills the BxHxH GEMM entirely.
//  * output/mask/cr recurrence depends only on `actions` -> exact integer
//    arithmetic in fp32; only `modes` depends on logits.
//
// GEMM pipe model (m134/m136 constants): A fragment from LDS (1 ds_read_b128
// per kk), B fragment direct from global W1 (L1/L2-resident, 16-lane
// same-line requests merged by the coalescer), 4x8 register blocking ->
// LDS pipe ~98k cyc/CU < FMA 131k cyc/CU => FMA-bound (was 3 LDS instr/kk,
// 295k cyc/CU, LDS-bound 2.25x).
// ---------------------------------------------------------------------------

#define NROW 64
#define NBLK 2048            // 131072 / 64

// LDS float offsets (flat, no overlays).
#define OFF_AT0  0           // AT[32][68] transposed X tile, buffer 0  (2176)
#define OFF_AT1  2176        // AT buffer 1                             (2176)
#define OFF_REDL 4352        // redL[4][64][3]  (sum, sumsq)            (768)
#define OFF_REDP 5120        // redP[4][64][9]  (6 used)                (2304)
#define OFF_EV   7424        // ev[4] wave entropy partials             (4)
#define OFF_W1B  7428        // W1bot[6][132]                           (792)
#define OFF_WC   8220        // skewed Wc: c*8 + (c>>3) + l             (1040)
#define OFF_CNT  9260        // cnt[64][11]                             (704)
#define LDS_N    9964        // 39856 bytes -> 4 blocks/CU by LDS

// d_out layout (floats): output[B][6], modes[B][4], lp[B], ent_mean[1]
#define OUT_MODES 786432
#define OUT_LP    1310720
#define OUT_ENT   1441792

// workspace float offsets
#define WS_WC  0             // 128*6
#define WS_BDP 768           // 6
#define WS_EP  1024          // 2048 block entropy partials

// ---------------------------------------------------------------------------
// prep: Wc = W2 @ Wd (128x6) -> ws[0..767]; bdp = b2 @ Wd + bd -> ws[768..773]
// ---------------------------------------------------------------------------
__global__ __launch_bounds__(256) void prep_kernel(
    const float* __restrict__ W2, const float* __restrict__ Wd,
    const float* __restrict__ b2, const float* __restrict__ bd,
    float* __restrict__ ws) {
  const int t = threadIdx.x;
  if (t < 128) {
    float a0 = 0.f, a1 = 0.f, a2 = 0.f, a3 = 0.f, a4 = 0.f, a5 = 0.f;
    for (int j = 0; j < 128; ++j) {
      const float w = W2[t * 128 + j];
      const float* wd = Wd + j * 6;
      a0 = fmaf(w, wd[0], a0); a1 = fmaf(w, wd[1], a1); a2 = fmaf(w, wd[2], a2);
      a3 = fmaf(w, wd[3], a3); a4 = fmaf(w, wd[4], a4); a5 = fmaf(w, wd[5], a5);
    }
    float* o = ws + WS_WC + t * 6;
    o[0] = a0; o[1] = a1; o[2] = a2; o[3] = a3; o[4] = a4; o[5] = a5;
  } else if (t < 134) {
    const int l = t - 128;
    float s = 0.f;
    for (int j = 0; j < 128; ++j) s = fmaf(b2[j], Wd[j * 6 + l], s);
    ws[WS_BDP + l] = bd[l] + s;
  }
}

// ---------------------------------------------------------------------------
// fused: base GEMM (X @ W1[0:256] + b1), then 4 recurrent iterations.
// ---------------------------------------------------------------------------
__global__ __launch_bounds__(256, 2) void fused_kernel(
    const float* __restrict__ X,    // [B][256]
    const float* __restrict__ CRES, // [B][6]
    const int*   __restrict__ ACT,  // [B][4]
    const float* __restrict__ HTM,  // [16]
    const int*   __restrict__ PHA,  // [B]
    const float* __restrict__ W1,   // [262][128]
    const float* __restrict__ B1,   // [128]
    const float* __restrict__ G,    // [128]
    const float* __restrict__ BETA, // [128]
    const float* __restrict__ WS,   // workspace (Wc, bdp)
    float* __restrict__ out,
    float* __restrict__ EP) {       // [NBLK] entropy partials
  __shared__ __align__(16) float lds[LDS_N];

  const int t    = threadIdx.x;
  const int tr   = t & 15;          // GEMM: row group (4 rows each)
  const int tc   = t >> 4;          // GEMM: col group (8 cols each)
  const int r0   = tr * 4;
  const int c0   = tc * 8;
  const int wv   = t >> 6;          // wave 0..3
  const int row  = t >> 2;          // softmax layout: local row 0..63
  const int part = t & 3;           // softmax layout: 4 lanes per row
  const long grow = (long)blockIdx.x * NROW + row;

  // ---- persistent small LDS staging (visible after first barrier) ----
  if (t < 192) {                    // W1 bottom rows (output-part of concat)
    const int j = t >> 5, c = (t & 31) * 4;
    *(float4*)&lds[OFF_W1B + j * 132 + c] =
        *(const float4*)(W1 + (size_t)(256 + j) * 128 + c);
  } else {                          // zero the counts buffer (rows 0..63)
    const int rr = t - 192;
#pragma unroll
    for (int j = 0; j < 11; ++j) lds[OFF_CNT + rr * 11 + j] = 0.f;
  }
  if (t < 128) {                    // skewed Wc: element (c,l) at c*8+(c>>3)+l
#pragma unroll
    for (int l = 0; l < 6; ++l)
      lds[OFF_WC + t * 8 + (t >> 3) + l] = WS[WS_WC + t * 6 + l];
  }

  // ---- GEMM helpers ----
  const float* xrow = X + (size_t)grow * 256;
  const int xoff = part * 8;

  auto load_x = [&](int th, float4& x0, float4& x1) {
    x0 = *(const float4*)(xrow + th * 32 + xoff);
    x1 = *(const float4*)(xrow + th * 32 + xoff + 4);
  };
  // AT stores: transpose X into AT[kk][row]; 4-way bank aliasing on the
  // scalar stores is unavoidable and cheap (8 stores per thread per tile).
  auto write_tile = [&](int atbase, const float4& x0, const float4& x1) {
    float* d = &lds[atbase + row];
    d[(xoff + 0) * 68] = x0.x; d[(xoff + 1) * 68] = x0.y;
    d[(xoff + 2) * 68] = x0.z; d[(xoff + 3) * 68] = x0.w;
    d[(xoff + 4) * 68] = x1.x; d[(xoff + 5) * 68] = x1.y;
    d[(xoff + 6) * 68] = x1.z; d[(xoff + 7) * 68] = x1.w;
  };
  // B group load: 4 kk-steps worth of this thread's 8 columns, direct from
  // global (L1/L2-hot W1). 16 lanes/instr share addresses -> coalesced.
  auto load_group = [&](const float* wb, int g, float4 (&Bb)[8]) {
    const float* p = wb + g * 512;            // 4 rows of 128
    Bb[0] = *(const float4*)(p + 0);   Bb[1] = *(const float4*)(p + 4);
    Bb[2] = *(const float4*)(p + 128); Bb[3] = *(const float4*)(p + 132);
    Bb[4] = *(const float4*)(p + 256); Bb[5] = *(const float4*)(p + 260);
    Bb[6] = *(const float4*)(p + 384); Bb[7] = *(const float4*)(p + 388);
  };

  float acc[4][8];
  {
    const float4 o0 = *(const float4*)(B1 + c0);
    const float4 o1 = *(const float4*)(B1 + c0 + 4);
    const float bi[8] = {o0.x, o0.y, o0.z, o0.w, o1.x, o1.y, o1.z, o1.w};
#pragma unroll
    for (int m = 0; m < 4; ++m)
#pragma unroll
      for (int cc = 0; cc < 8; ++cc) acc[m][cc] = bi[cc];
  }

  auto compute_group = [&](int atbase, int g, const float4 (&Bb)[8]) {
#pragma unroll
    for (int q = 0; q < 4; ++q) {
      const float4 a4 = *(const float4*)&lds[atbase + (g * 4 + q) * 68 + r0];
      const float av[4] = {a4.x, a4.y, a4.z, a4.w};
      const float4 bl = Bb[2 * q], bh = Bb[2 * q + 1];
      const float bv[8] = {bl.x, bl.y, bl.z, bl.w, bh.x, bh.y, bh.z, bh.w};
#pragma unroll
      for (int m = 0; m < 4; ++m)
#pragma unroll
        for (int cc = 0; cc < 8; ++cc)
          acc[m][cc] = fmaf(av[m], bv[cc], acc[m][cc]);
    }
  };
  // 32 kk-steps: B register double-buffer at 4-kk granularity, loads one
  // group ahead of use (group compute ~300 cyc wall >> L1/L2 latency).
  auto compute_tile = [&](int atbase, int ti) {
    const float* wb = W1 + (size_t)(ti * 32) * 128 + c0;
    float4 Bb0[8], Bb1[8];
    load_group(wb, 0, Bb0);
    load_group(wb, 1, Bb1);
    compute_group(atbase, 0, Bb0);
    load_group(wb, 2, Bb0);
    compute_group(atbase, 1, Bb1);
    load_group(wb, 3, Bb1);
    compute_group(atbase, 2, Bb0);
    load_group(wb, 4, Bb0);
    compute_group(atbase, 3, Bb1);
    load_group(wb, 5, Bb1);
    compute_group(atbase, 4, Bb0);
    load_group(wb, 6, Bb0);
    compute_group(atbase, 5, Bb1);
    load_group(wb, 7, Bb1);
    compute_group(atbase, 6, Bb0);
    compute_group(atbase, 7, Bb1);
  };

  // ---- epilogue-phase state (loaded late, inside last GEMM step) ----
  float gm[8], bt[8], bdpr[6], cr[6];
  int4 act;
  float hm;

  // ---- prologue: X tile0 -> AT0; tile1 prefetched to registers ----
  float4 xa0, xa1, xb0, xb1;
  load_x(0, xa0, xa1);
  load_x(1, xb0, xb1);
  write_tile(OFF_AT0, xa0, xa1);
  __syncthreads();                  // AT0 + small staging visible

  // ---- GEMM: 8 tiles, LDS double-buffered A, 1 barrier per tile ----
#pragma unroll 1
  for (int p = 0; p < 4; ++p) {
    // even tile 2p: AT0 ready; xb holds X tile 2p+1
    write_tile(OFF_AT1, xb0, xb1);
    if (p < 3) load_x(2 * p + 2, xa0, xa1);
    compute_tile(OFF_AT0, 2 * p);
    __syncthreads();                // AT1 ready; AT0 dead
    // odd tile 2p+1: AT1 ready; xa holds X tile 2p+2 (if any)
    if (p < 3) {
      write_tile(OFF_AT0, xa0, xa1);
      load_x(2 * p + 3, xb0, xb1);
    }
    if (p == 3) {                   // hide iteration-phase loads under tile 7
      const float4 g0 = *(const float4*)(G + c0);
      const float4 g1 = *(const float4*)(G + c0 + 4);
      gm[0] = g0.x; gm[1] = g0.y; gm[2] = g0.z; gm[3] = g0.w;
      gm[4] = g1.x; gm[5] = g1.y; gm[6] = g1.z; gm[7] = g1.w;
      const float4 e0 = *(const float4*)(BETA + c0);
      const float4 e1 = *(const float4*)(BETA + c0 + 4);
      bt[0] = e0.x; bt[1] = e0.y; bt[2] = e0.z; bt[3] = e0.w;
      bt[4] = e1.x; bt[5] = e1.y; bt[6] = e1.z; bt[7] = e1.w;
#pragma unroll
      for (int l = 0; l < 6; ++l) bdpr[l] = WS[WS_BDP + l];
      const float2* cp = (const float2*)(CRES + grow * 6);
      const float2 ca = cp[0], cb = cp[1], cc2 = cp[2];
      cr[0] = ca.x; cr[1] = ca.y; cr[2] = cb.x;
      cr[3] = cb.y; cr[4] = cc2.x; cr[5] = cc2.y;
      act = ((const int4*)ACT)[grow];
      hm = HTM[PHA[grow]];
    }
    compute_tile(OFF_AT1, 2 * p + 1);
    __syncthreads();                // AT0 ready for next p (or GEMM done)
  }

  // ---- remaining per-row state (pure VALU) ----
  float msk[6], cnt[6] = {0.f, 0.f, 0.f, 0.f, 0.f, 0.f};
  {
    const float s = cr[0] + cr[1] + cr[2] + cr[3] + cr[4] + cr[5];
#pragma unroll
    for (int j = 0; j < 6; ++j) msk[j] = (cr[j] > 0.f) ? 1.f : 0.f;
    msk[0] = (s == 0.f) ? 1.f : 0.f;           // initial slot-0 rule
  }
  float lpsum = 0.f, entsum = 0.f;
  float modesf[4];

  // ---- 4 recurrent iterations (fully unrolled, static indexing only) ----
#pragma unroll
  for (int it = 0; it < 4; ++it) {
    // 1) hpre = base + counts @ W1bot
    float hp[4][8];
#pragma unroll
    for (int m = 0; m < 4; ++m)
#pragma unroll
      for (int cc = 0; cc < 8; ++cc) hp[m][cc] = acc[m][cc];
    if (it > 0) {
#pragma unroll
      for (int j = 1; j < 6; ++j) {
        const float4 w0 = *(const float4*)&lds[OFF_W1B + j * 132 + c0];
        const float4 w4 = *(const float4*)&lds[OFF_W1B + j * 132 + c0 + 4];
        const float wv8[8] = {w0.x, w0.y, w0.z, w0.w, w4.x, w4.y, w4.z, w4.w};
#pragma unroll
        for (int m = 0; m < 4; ++m) {
          const float cj = lds[OFF_CNT + (r0 + m) * 11 + j];
#pragma unroll
          for (int cc = 0; cc < 8; ++cc)
            hp[m][cc] = fmaf(cj, wv8[cc], hp[m][cc]);
        }
      }
    }

    // 2) LayerNorm stats, single pass (var = E[x^2] - mu^2; mu^2/E[x^2]~1e-2,
    //    no cancellation risk beyond inherent ~1e-7 reassociation noise)
    float mu[4], rs[4];
    {
      float sx[4], sq[4];
#pragma unroll
      for (int m = 0; m < 4; ++m) {
        float a = 0.f, b = 0.f;
#pragma unroll
        for (int cc = 0; cc < 8; ++cc) {
          a += hp[m][cc];
          b = fmaf(hp[m][cc], hp[m][cc], b);
        }
        a += __shfl_xor(a, 16, 64); a += __shfl_xor(a, 32, 64);
        b += __shfl_xor(b, 16, 64); b += __shfl_xor(b, 32, 64);
        sx[m] = a; sq[m] = b;
      }
      if ((tc & 3) == 0) {
#pragma unroll
        for (int m = 0; m < 4; ++m) {
          lds[OFF_REDL + (wv * 64 + r0 + m) * 3 + 0] = sx[m];
          lds[OFF_REDL + (wv * 64 + r0 + m) * 3 + 1] = sq[m];
        }
      }
    }
    __syncthreads();
#pragma unroll
    for (int m = 0; m < 4; ++m) {
      float a = 0.f, b = 0.f;
#pragma unroll
      for (int w = 0; w < 4; ++w) {
        a += lds[OFF_REDL + (w * 64 + r0 + m) * 3 + 0];
        b += lds[OFF_REDL + (w * 64 + r0 + m) * 3 + 1];
      }
      mu[m] = a * (1.f / 128.f);
      const float var = b * (1.f / 128.f) - mu[m] * mu[m];
      rs[m] = 1.f / sqrtf(var + 1e-5f);
    }

    // 3) relu(LN) -> partial logits against skewed Wc
    float pl[4][6];
#pragma unroll
    for (int m = 0; m < 4; ++m)
#pragma unroll
      for (int l = 0; l < 6; ++l) pl[m][l] = 0.f;
#pragma unroll
    for (int m = 0; m < 4; ++m) {
#pragma unroll
      for (int cc = 0; cc < 8; ++cc) {
        float v = (hp[m][cc] - mu[m]) * rs[m];
        v = fmaf(v, gm[cc], bt[cc]);
        v = fmaxf(v, 0.f);
        const float* wp = &lds[OFF_WC + (c0 + cc) * 8 + tc];
#pragma unroll
        for (int l = 0; l < 6; ++l) pl[m][l] = fmaf(v, wp[l], pl[m][l]);
      }
    }
#pragma unroll
    for (int m = 0; m < 4; ++m)
#pragma unroll
      for (int l = 0; l < 6; ++l) {
        float a = pl[m][l];
        a += __shfl_xor(a, 16, 64); a += __shfl_xor(a, 32, 64);
        pl[m][l] = a;
      }
    {
      const int q = tc & 3;
#pragma unroll
      for (int mm = 0; mm < 4; ++mm)
        if (q == mm) {
#pragma unroll
          for (int l = 0; l < 6; ++l)
            lds[OFF_REDP + (wv * 64 + r0 + mm) * 9 + l] = pl[mm][l];
        }
    }
    __syncthreads();

    // 4) per-row masked log-softmax (softmax layout, 4 redundant lanes/row)
    float lg[6];
#pragma unroll
    for (int l = 0; l < 6; ++l) {
      float a = lds[OFF_REDP + row * 9 + l];
      a += lds[OFF_REDP + (64 + row) * 9 + l];
      a += lds[OFF_REDP + (128 + row) * 9 + l];
      a += lds[OFF_REDP + (192 + row) * 9 + l];
      lg[l] = a + bdpr[l];
    }
    float ml[6];
#pragma unroll
    for (int l = 0; l < 6; ++l)
      ml[l] = (msk[l] > 0.f) ? lg[l] : -1000000000.0f;
    float mx = ml[0];
    int bi = 0;
#pragma unroll
    for (int l = 1; l < 6; ++l)
      if (ml[l] > mx) { mx = ml[l]; bi = l; }   // strict > : first-max, as jnp
    modesf[it] = (float)bi;
    float sh[6], e[6], se = 0.f;
#pragma unroll
    for (int l = 0; l < 6; ++l) {
      sh[l] = ml[l] - mx;
      e[l] = expf(sh[l]);
      se += e[l];
    }
    const float lse = logf(se);
    const float ise = 1.f / se;
    float ent = 0.f;
#pragma unroll
    for (int l = 0; l < 6; ++l)
      ent -= (e[l] * ise) * (sh[l] - lse);   // -(p * logp); masked -> exact 0
    const int a = (it == 0) ? act.x : (it == 1) ? act.y : (it == 2) ? act.z : act.w;
    float lp = -lse;
#pragma unroll
    for (int l = 0; l < 6; ++l)
      if (l == a) lp += sh[l];
    if (it > 0) {
      const int ap = (it == 1) ? act.x : (it == 2) ? act.y : act.z;
      const float mp = (ap > 0) ? 1.f : 0.f;
      lp *= mp;
      ent *= mp;
    }
    lpsum += lp;
    entsum += ent;

    // 5) state update (exact integer arithmetic; static indexing)
#pragma unroll
    for (int l = 0; l < 6; ++l) {
      if (l == a) {
        if (l > 0) cnt[l] += 1.f;
        cr[l] = fmaxf(cr[l] - 1.f, 0.f);
      }
      msk[l] = (cr[l] > 0.f) ? 1.f : 0.f;
    }
    msk[0] = 1.f;
    if (part == 0 && it < 3) {
#pragma unroll
      for (int j = 1; j < 6; ++j) lds[OFF_CNT + row * 11 + j] = cnt[j];
    }
    __syncthreads();
  }

  // ---- final outputs ----
  if (part == 0) {
    *(float2*)(out + grow * 6) = make_float2(cnt[0], cnt[1]);
  } else if (part == 1) {
    *(float2*)(out + grow * 6 + 2) = make_float2(cnt[2], cnt[3]);
  } else if (part == 2) {
    *(float2*)(out + grow * 6 + 4) = make_float2(cnt[4], cnt[5]);
  }
  if (part == 0) {
    *(float4*)(out + OUT_MODES + grow * 4) =
        make_float4(modesf[0], modesf[1], modesf[2], modesf[3]);
    out[OUT_LP + grow] = lpsum * hm;
  }
  // deterministic per-block entropy partial
  float ev = (part == 0) ? entsum * hm : 0.f;
#pragma unroll
  for (int off = 1; off < 64; off <<= 1) ev += __shfl_xor(ev, off, 64);
  if ((t & 63) == 0) lds[OFF_EV + wv] = ev;
  __syncthreads();
  if (t == 0)
    EP[blockIdx.x] =
        lds[OFF_EV] + lds[OFF_EV + 1] + lds[OFF_EV + 2] + lds[OFF_EV + 3];
}

// ---------------------------------------------------------------------------
// deterministic final reduction of 2048 block partials -> ent mean
// ---------------------------------------------------------------------------
__global__ __launch_bounds__(256) void ent_reduce(const float* __restrict__ EP,
                                                  float* __restrict__ out) {
  const int t = threadIdx.x;
  float s = 0.f;
#pragma unroll
  for (int i = 0; i < 8; ++i) s += EP[t + 256 * i];
#pragma unroll
  for (int off = 1; off < 64; off <<= 1) s += __shfl_xor(s, off, 64);
  __shared__ float w[4];
  if ((t & 63) == 0) w[t >> 6] = s;
  __syncthreads();
  if (t == 0)
    out[OUT_ENT] = (w[0] + w[1] + w[2] + w[3]) * (1.f / 131072.f);
}

// ---------------------------------------------------------------------------
extern "C" void kernel_launch(void* const* d_in, const int* in_sizes, int n_in,
                              void* d_out, int out_size, void* d_ws, size_t ws_size,
                              hipStream_t stream) {
  (void)in_sizes; (void)n_in; (void)out_size; (void)ws_size;
  const float* main_inputs = (const float*)d_in[0];
  const float* cur_res     = (const float*)d_in[1];
  const int*   actions     = (const int*)d_in[2];
  const float* htm         = (const float*)d_in[3];
  const int*   pha         = (const int*)d_in[4];
  const float* W1          = (const float*)d_in[5];
  const float* b1          = (const float*)d_in[6];
  const float* gamma       = (const float*)d_in[7];
  const float* beta        = (const float*)d_in[8];
  const float* W2          = (const float*)d_in[9];
  const float* b2          = (const float*)d_in[10];
  const float* Wd          = (const float*)d_in[11];
  const float* bd          = (const float*)d_in[12];
  float* out = (float*)d_out;
  float* ws  = (float*)d_ws;

  prep_kernel<<<1, 256, 0, stream>>>(W2, Wd, b2, bd, ws);
  fused_kernel<<<NBLK, 256, 0, stream>>>(main_inputs, cur_res, actions, htm,
                                         pha, W1, b1, gamma, beta, ws, out,
                                         ws + WS_EP);
  ent_reduce<<<1, 256, 0, stream>>>(ws + WS_EP, out);
}

// Round 5
// 530.453 us; speedup vs baseline: 1.8047x; 1.8047x over previous
//
#include <hip/hip_runtime.h>
#include <hip/hip_bf16.h>
#include <cstdint>

// ---------------------------------------------------------------------------
// RecurrentResourceActionHead — fused single-pass implementation.
//
// Key algebra:
//  * x = [main_inputs, output]; x@W1 = main@W1[0:256] (iteration-invariant,
//    computed ONCE) + counts@W1[256:262] (rank<=5 correction per iteration).
//  * h is unobserved: logits = relu(LN)@(W2@Wd) + (b2@Wd + bd). W2@Wd (128x6)
//    precomputed by prep_kernel -> kills the BxHxH GEMM entirely.
//  * output/mask/cr recurrence depends only on `actions` -> exact integer
//    arithmetic in fp32; only `modes` depends on logits.
//
// GEMM pipe model (m134/m136 constants): A fragment from LDS (1 ds_read_b128
// per kk), B fragment direct from global W1 (L1/L2-resident, 16-lane
// same-line requests merged by the coalescer), 4x8 register blocking ->
// LDS pipe ~98k cyc/CU < FMA 131k cyc/CU => FMA-bound.
//
// R4 lesson (rocprof): __launch_bounds__(256,2) capped VGPR at 128 and the
// B double-buffer spilled to scratch -> 2.45 GB/dispatch of HBM spill
// traffic, 815 us, VALUBusy 20%. Working set needs ~150-160 VGPR; bound
// relaxed to (256,1) so the allocator can keep B in registers.
// ---------------------------------------------------------------------------

#define NROW 64
#define NBLK 2048            // 131072 / 64

// LDS float offsets (flat, no overlays).
#define OFF_AT0  0           // AT[32][68] transposed X tile, buffer 0  (2176)
#define OFF_AT1  2176        // AT buffer 1                             (2176)
#define OFF_REDL 4352        // redL[4][64][3]  (sum, sumsq)            (768)
#define OFF_REDP 5120        // redP[4][64][9]  (6 used)                (2304)
#define OFF_EV   7424        // ev[4] wave entropy partials             (4)
#define OFF_W1B  7428        // W1bot[6][132]                           (792)
#define OFF_WC   8220        // skewed Wc: c*8 + (c>>3) + l             (1040)
#define OFF_CNT  9260        // cnt[64][11]                             (704)
#define LDS_N    9964        // 39856 bytes

// d_out layout (floats): output[B][6], modes[B][4], lp[B], ent_mean[1]
#define OUT_MODES 786432
#define OUT_LP    1310720
#define OUT_ENT   1441792

// workspace float offsets
#define WS_WC  0             // 128*6
#define WS_BDP 768           // 6
#define WS_EP  1024          // 2048 block entropy partials

// ---------------------------------------------------------------------------
// prep: Wc = W2 @ Wd (128x6) -> ws[0..767]; bdp = b2 @ Wd + bd -> ws[768..773]
// ---------------------------------------------------------------------------
__global__ __launch_bounds__(256) void prep_kernel(
    const float* __restrict__ W2, const float* __restrict__ Wd,
    const float* __restrict__ b2, const float* __restrict__ bd,
    float* __restrict__ ws) {
  const int t = threadIdx.x;
  if (t < 128) {
    float a0 = 0.f, a1 = 0.f, a2 = 0.f, a3 = 0.f, a4 = 0.f, a5 = 0.f;
    for (int j = 0; j < 128; ++j) {
      const float w = W2[t * 128 + j];
      const float* wd = Wd + j * 6;
      a0 = fmaf(w, wd[0], a0); a1 = fmaf(w, wd[1], a1); a2 = fmaf(w, wd[2], a2);
      a3 = fmaf(w, wd[3], a3); a4 = fmaf(w, wd[4], a4); a5 = fmaf(w, wd[5], a5);
    }
    float* o = ws + WS_WC + t * 6;
    o[0] = a0; o[1] = a1; o[2] = a2; o[3] = a3; o[4] = a4; o[5] = a5;
  } else if (t < 134) {
    const int l = t - 128;
    float s = 0.f;
    for (int j = 0; j < 128; ++j) s = fmaf(b2[j], Wd[j * 6 + l], s);
    ws[WS_BDP + l] = bd[l] + s;
  }
}

// ---------------------------------------------------------------------------
// fused: base GEMM (X @ W1[0:256] + b1), then 4 recurrent iterations.
// ---------------------------------------------------------------------------
__global__ __launch_bounds__(256, 1) void fused_kernel(
    const float* __restrict__ X,    // [B][256]
    const float* __restrict__ CRES, // [B][6]
    const int*   __restrict__ ACT,  // [B][4]
    const float* __restrict__ HTM,  // [16]
    const int*   __restrict__ PHA,  // [B]
    const float* __restrict__ W1,   // [262][128]
    const float* __restrict__ B1,   // [128]
    const float* __restrict__ G,    // [128]
    const float* __restrict__ BETA, // [128]
    const float* __restrict__ WS,   // workspace (Wc, bdp)
    float* __restrict__ out,
    float* __restrict__ EP) {       // [NBLK] entropy partials
  __shared__ __align__(16) float lds[LDS_N];

  const int t    = threadIdx.x;
  const int tr   = t & 15;          // GEMM: row group (4 rows each)
  const int tc   = t >> 4;          // GEMM: col group (8 cols each)
  const int r0   = tr * 4;
  const int c0   = tc * 8;
  const int wv   = t >> 6;          // wave 0..3
  const int row  = t >> 2;          // softmax layout: local row 0..63
  const int part = t & 3;           // softmax layout: 4 lanes per row
  const long grow = (long)blockIdx.x * NROW + row;

  // ---- persistent small LDS staging (visible after first barrier) ----
  if (t < 192) {                    // W1 bottom rows (output-part of concat)
    const int j = t >> 5, c = (t & 31) * 4;
    *(float4*)&lds[OFF_W1B + j * 132 + c] =
        *(const float4*)(W1 + (size_t)(256 + j) * 128 + c);
  } else {                          // zero the counts buffer (rows 0..63)
    const int rr = t - 192;
#pragma unroll
    for (int j = 0; j < 11; ++j) lds[OFF_CNT + rr * 11 + j] = 0.f;
  }
  if (t < 128) {                    // skewed Wc: element (c,l) at c*8+(c>>3)+l
#pragma unroll
    for (int l = 0; l < 6; ++l)
      lds[OFF_WC + t * 8 + (t >> 3) + l] = WS[WS_WC + t * 6 + l];
  }

  // ---- GEMM helpers ----
  const float* xrow = X + (size_t)grow * 256;
  const int xoff = part * 8;

  auto load_x = [&](int th, float4& x0, float4& x1) {
    x0 = *(const float4*)(xrow + th * 32 + xoff);
    x1 = *(const float4*)(xrow + th * 32 + xoff + 4);
  };
  // AT stores: transpose X into AT[kk][row]; 4-way bank aliasing on the
  // scalar stores is unavoidable and cheap (8 stores per thread per tile).
  auto write_tile = [&](int atbase, const float4& x0, const float4& x1) {
    float* d = &lds[atbase + row];
    d[(xoff + 0) * 68] = x0.x; d[(xoff + 1) * 68] = x0.y;
    d[(xoff + 2) * 68] = x0.z; d[(xoff + 3) * 68] = x0.w;
    d[(xoff + 4) * 68] = x1.x; d[(xoff + 5) * 68] = x1.y;
    d[(xoff + 6) * 68] = x1.z; d[(xoff + 7) * 68] = x1.w;
  };
  // B group load: 4 kk-steps worth of this thread's 8 columns, direct from
  // global (L1/L2-hot W1). 16 lanes/instr share addresses -> coalesced.
  auto load_group = [&](const float* wb, int g, float4 (&Bb)[8]) {
    const float* p = wb + g * 512;            // 4 rows of 128
    Bb[0] = *(const float4*)(p + 0);   Bb[1] = *(const float4*)(p + 4);
    Bb[2] = *(const float4*)(p + 128); Bb[3] = *(const float4*)(p + 132);
    Bb[4] = *(const float4*)(p + 256); Bb[5] = *(const float4*)(p + 260);
    Bb[6] = *(const float4*)(p + 384); Bb[7] = *(const float4*)(p + 388);
  };

  float acc[4][8];
  {
    const float4 o0 = *(const float4*)(B1 + c0);
    const float4 o1 = *(const float4*)(B1 + c0 + 4);
    const float bi[8] = {o0.x, o0.y, o0.z, o0.w, o1.x, o1.y, o1.z, o1.w};
#pragma unroll
    for (int m = 0; m < 4; ++m)
#pragma unroll
      for (int cc = 0; cc < 8; ++cc) acc[m][cc] = bi[cc];
  }

  auto compute_group = [&](int atbase, int g, const float4 (&Bb)[8]) {
#pragma unroll
    for (int q = 0; q < 4; ++q) {
      const float4 a4 = *(const float4*)&lds[atbase + (g * 4 + q) * 68 + r0];
      const float av[4] = {a4.x, a4.y, a4.z, a4.w};
      const float4 bl = Bb[2 * q], bh = Bb[2 * q + 1];
      const float bv[8] = {bl.x, bl.y, bl.z, bl.w, bh.x, bh.y, bh.z, bh.w};
#pragma unroll
      for (int m = 0; m < 4; ++m)
#pragma unroll
        for (int cc = 0; cc < 8; ++cc)
          acc[m][cc] = fmaf(av[m], bv[cc], acc[m][cc]);
    }
  };
  // 32 kk-steps: B register double-buffer at 4-kk granularity, loads one
  // group ahead of use (group compute ~300 cyc wall >> L1/L2 latency).
  auto compute_tile = [&](int atbase, int ti) {
    const float* wb = W1 + (size_t)(ti * 32) * 128 + c0;
    float4 Bb0[8], Bb1[8];
    load_group(wb, 0, Bb0);
    load_group(wb, 1, Bb1);
    compute_group(atbase, 0, Bb0);
    load_group(wb, 2, Bb0);
    compute_group(atbase, 1, Bb1);
    load_group(wb, 3, Bb1);
    compute_group(atbase, 2, Bb0);
    load_group(wb, 4, Bb0);
    compute_group(atbase, 3, Bb1);
    load_group(wb, 5, Bb1);
    compute_group(atbase, 4, Bb0);
    load_group(wb, 6, Bb0);
    compute_group(atbase, 5, Bb1);
    load_group(wb, 7, Bb1);
    compute_group(atbase, 6, Bb0);
    compute_group(atbase, 7, Bb1);
  };

  // ---- epilogue-phase state (loaded late, inside last GEMM step) ----
  float gm[8], bt[8], bdpr[6], cr[6];
  int4 act;
  float hm;

  // ---- prologue: X tile0 -> AT0; tile1 prefetched to registers ----
  float4 xa0, xa1, xb0, xb1;
  load_x(0, xa0, xa1);
  load_x(1, xb0, xb1);
  write_tile(OFF_AT0, xa0, xa1);
  __syncthreads();                  // AT0 + small staging visible

  // ---- GEMM: 8 tiles, LDS double-buffered A, 1 barrier per tile ----
#pragma unroll 1
  for (int p = 0; p < 4; ++p) {
    // even tile 2p: AT0 ready; xb holds X tile 2p+1
    write_tile(OFF_AT1, xb0, xb1);
    if (p < 3) load_x(2 * p + 2, xa0, xa1);
    compute_tile(OFF_AT0, 2 * p);
    __syncthreads();                // AT1 ready; AT0 dead
    // odd tile 2p+1: AT1 ready; xa holds X tile 2p+2 (if any)
    if (p < 3) {
      write_tile(OFF_AT0, xa0, xa1);
      load_x(2 * p + 3, xb0, xb1);
    }
    if (p == 3) {                   // hide iteration-phase loads under tile 7
      const float4 g0 = *(const float4*)(G + c0);
      const float4 g1 = *(const float4*)(G + c0 + 4);
      gm[0] = g0.x; gm[1] = g0.y; gm[2] = g0.z; gm[3] = g0.w;
      gm[4] = g1.x; gm[5] = g1.y; gm[6] = g1.z; gm[7] = g1.w;
      const float4 e0 = *(const float4*)(BETA + c0);
      const float4 e1 = *(const float4*)(BETA + c0 + 4);
      bt[0] = e0.x; bt[1] = e0.y; bt[2] = e0.z; bt[3] = e0.w;
      bt[4] = e1.x; bt[5] = e1.y; bt[6] = e1.z; bt[7] = e1.w;
#pragma unroll
      for (int l = 0; l < 6; ++l) bdpr[l] = WS[WS_BDP + l];
      const float2* cp = (const float2*)(CRES + grow * 6);
      const float2 ca = cp[0], cb = cp[1], cc2 = cp[2];
      cr[0] = ca.x; cr[1] = ca.y; cr[2] = cb.x;
      cr[3] = cb.y; cr[4] = cc2.x; cr[5] = cc2.y;
      act = ((const int4*)ACT)[grow];
      hm = HTM[PHA[grow]];
    }
    compute_tile(OFF_AT1, 2 * p + 1);
    __syncthreads();                // AT0 ready for next p (or GEMM done)
  }

  // ---- remaining per-row state (pure VALU) ----
  float msk[6], cnt[6] = {0.f, 0.f, 0.f, 0.f, 0.f, 0.f};
  {
    const float s = cr[0] + cr[1] + cr[2] + cr[3] + cr[4] + cr[5];
#pragma unroll
    for (int j = 0; j < 6; ++j) msk[j] = (cr[j] > 0.f) ? 1.f : 0.f;
    msk[0] = (s == 0.f) ? 1.f : 0.f;           // initial slot-0 rule
  }
  float lpsum = 0.f, entsum = 0.f;
  float modesf[4];

  // ---- 4 recurrent iterations (fully unrolled, static indexing only) ----
#pragma unroll
  for (int it = 0; it < 4; ++it) {
    // 1) hpre = base + counts @ W1bot
    float hp[4][8];
#pragma unroll
    for (int m = 0; m < 4; ++m)
#pragma unroll
      for (int cc = 0; cc < 8; ++cc) hp[m][cc] = acc[m][cc];
    if (it > 0) {
#pragma unroll
      for (int j = 1; j < 6; ++j) {
        const float4 w0 = *(const float4*)&lds[OFF_W1B + j * 132 + c0];
        const float4 w4 = *(const float4*)&lds[OFF_W1B + j * 132 + c0 + 4];
        const float wv8[8] = {w0.x, w0.y, w0.z, w0.w, w4.x, w4.y, w4.z, w4.w};
#pragma unroll
        for (int m = 0; m < 4; ++m) {
          const float cj = lds[OFF_CNT + (r0 + m) * 11 + j];
#pragma unroll
          for (int cc = 0; cc < 8; ++cc)
            hp[m][cc] = fmaf(cj, wv8[cc], hp[m][cc]);
        }
      }
    }

    // 2) LayerNorm stats, single pass (var = E[x^2] - mu^2; mu^2/E[x^2]~1e-2,
    //    no cancellation risk beyond inherent ~1e-7 reassociation noise)
    float mu[4], rs[4];
    {
      float sx[4], sq[4];
#pragma unroll
      for (int m = 0; m < 4; ++m) {
        float a = 0.f, b = 0.f;
#pragma unroll
        for (int cc = 0; cc < 8; ++cc) {
          a += hp[m][cc];
          b = fmaf(hp[m][cc], hp[m][cc], b);
        }
        a += __shfl_xor(a, 16, 64); a += __shfl_xor(a, 32, 64);
        b += __shfl_xor(b, 16, 64); b += __shfl_xor(b, 32, 64);
        sx[m] = a; sq[m] = b;
      }
      if ((tc & 3) == 0) {
#pragma unroll
        for (int m = 0; m < 4; ++m) {
          lds[OFF_REDL + (wv * 64 + r0 + m) * 3 + 0] = sx[m];
          lds[OFF_REDL + (wv * 64 + r0 + m) * 3 + 1] = sq[m];
        }
      }
    }
    __syncthreads();
#pragma unroll
    for (int m = 0; m < 4; ++m) {
      float a = 0.f, b = 0.f;
#pragma unroll
      for (int w = 0; w < 4; ++w) {
        a += lds[OFF_REDL + (w * 64 + r0 + m) * 3 + 0];
        b += lds[OFF_REDL + (w * 64 + r0 + m) * 3 + 1];
      }
      mu[m] = a * (1.f / 128.f);
      const float var = b * (1.f / 128.f) - mu[m] * mu[m];
      rs[m] = 1.f / sqrtf(var + 1e-5f);
    }

    // 3) relu(LN) -> partial logits against skewed Wc
    float pl[4][6];
#pragma unroll
    for (int m = 0; m < 4; ++m)
#pragma unroll
      for (int l = 0; l < 6; ++l) pl[m][l] = 0.f;
#pragma unroll
    for (int m = 0; m < 4; ++m) {
#pragma unroll
      for (int cc = 0; cc < 8; ++cc) {
        float v = (hp[m][cc] - mu[m]) * rs[m];
        v = fmaf(v, gm[cc], bt[cc]);
        v = fmaxf(v, 0.f);
        const float* wp = &lds[OFF_WC + (c0 + cc) * 8 + tc];
#pragma unroll
        for (int l = 0; l < 6; ++l) pl[m][l] = fmaf(v, wp[l], pl[m][l]);
      }
    }
#pragma unroll
    for (int m = 0; m < 4; ++m)
#pragma unroll
      for (int l = 0; l < 6; ++l) {
        float a = pl[m][l];
        a += __shfl_xor(a, 16, 64); a += __shfl_xor(a, 32, 64);
        pl[m][l] = a;
      }
    {
      const int q = tc & 3;
#pragma unroll
      for (int mm = 0; mm < 4; ++mm)
        if (q == mm) {
#pragma unroll
          for (int l = 0; l < 6; ++l)
            lds[OFF_REDP + (wv * 64 + r0 + mm) * 9 + l] = pl[mm][l];
        }
    }
    __syncthreads();

    // 4) per-row masked log-softmax (softmax layout, 4 redundant lanes/row)
    float lg[6];
#pragma unroll
    for (int l = 0; l < 6; ++l) {
      float a = lds[OFF_REDP + row * 9 + l];
      a += lds[OFF_REDP + (64 + row) * 9 + l];
      a += lds[OFF_REDP + (128 + row) * 9 + l];
      a += lds[OFF_REDP + (192 + row) * 9 + l];
      lg[l] = a + bdpr[l];
    }
    float ml[6];
#pragma unroll
    for (int l = 0; l < 6; ++l)
      ml[l] = (msk[l] > 0.f) ? lg[l] : -1000000000.0f;
    float mx = ml[0];
    int bi = 0;
#pragma unroll
    for (int l = 1; l < 6; ++l)
      if (ml[l] > mx) { mx = ml[l]; bi = l; }   // strict > : first-max, as jnp
    modesf[it] = (float)bi;
    float sh[6], e[6], se = 0.f;
#pragma unroll
    for (int l = 0; l < 6; ++l) {
      sh[l] = ml[l] - mx;
      e[l] = expf(sh[l]);
      se += e[l];
    }
    const float lse = logf(se);
    const float ise = 1.f / se;
    float ent = 0.f;
#pragma unroll
    for (int l = 0; l < 6; ++l)
      ent -= (e[l] * ise) * (sh[l] - lse);   // -(p * logp); masked -> exact 0
    const int a = (it == 0) ? act.x : (it == 1) ? act.y : (it == 2) ? act.z : act.w;
    float lp = -lse;
#pragma unroll
    for (int l = 0; l < 6; ++l)
      if (l == a) lp += sh[l];
    if (it > 0) {
      const int ap = (it == 1) ? act.x : (it == 2) ? act.y : act.z;
      const float mp = (ap > 0) ? 1.f : 0.f;
      lp *= mp;
      ent *= mp;
    }
    lpsum += lp;
    entsum += ent;

    // 5) state update (exact integer arithmetic; static indexing)
#pragma unroll
    for (int l = 0; l < 6; ++l) {
      if (l == a) {
        if (l > 0) cnt[l] += 1.f;
        cr[l] = fmaxf(cr[l] - 1.f, 0.f);
      }
      msk[l] = (cr[l] > 0.f) ? 1.f : 0.f;
    }
    msk[0] = 1.f;
    if (part == 0 && it < 3) {
#pragma unroll
      for (int j = 1; j < 6; ++j) lds[OFF_CNT + row * 11 + j] = cnt[j];
    }
    __syncthreads();
  }

  // ---- final outputs ----
  if (part == 0) {
    *(float2*)(out + grow * 6) = make_float2(cnt[0], cnt[1]);
  } else if (part == 1) {
    *(float2*)(out + grow * 6 + 2) = make_float2(cnt[2], cnt[3]);
  } else if (part == 2) {
    *(float2*)(out + grow * 6 + 4) = make_float2(cnt[4], cnt[5]);
  }
  if (part == 0) {
    *(float4*)(out + OUT_MODES + grow * 4) =
        make_float4(modesf[0], modesf[1], modesf[2], modesf[3]);
    out[OUT_LP + grow] = lpsum * hm;
  }
  // deterministic per-block entropy partial
  float ev = (part == 0) ? entsum * hm : 0.f;
#pragma unroll
  for (int off = 1; off < 64; off <<= 1) ev += __shfl_xor(ev, off, 64);
  if ((t & 63) == 0) lds[OFF_EV + wv] = ev;
  __syncthreads();
  if (t == 0)
    EP[blockIdx.x] =
        lds[OFF_EV] + lds[OFF_EV + 1] + lds[OFF_EV + 2] + lds[OFF_EV + 3];
}

// ---------------------------------------------------------------------------
// deterministic final reduction of 2048 block partials -> ent mean
// ---------------------------------------------------------------------------
__global__ __launch_bounds__(256) void ent_reduce(const float* __restrict__ EP,
                                                  float* __restrict__ out) {
  const int t = threadIdx.x;
  float s = 0.f;
#pragma unroll
  for (int i = 0; i < 8; ++i) s += EP[t + 256 * i];
#pragma unroll
  for (int off = 1; off < 64; off <<= 1) s += __shfl_xor(s, off, 64);
  __shared__ float w[4];
  if ((t & 63) == 0) w[t >> 6] = s;
  __syncthreads();
  if (t == 0)
    out[OUT_ENT] = (w[0] + w[1] + w[2] + w[3]) * (1.f / 131072.f);
}

// ---------------------------------------------------------------------------
extern "C" void kernel_launch(void* const* d_in, const int* in_sizes, int n_in,
                              void* d_out, int out_size, void* d_ws, size_t ws_size,
                              hipStream_t stream) {
  (void)in_sizes; (void)n_in; (void)out_size; (void)ws_size;
  const float* main_inputs = (const float*)d_in[0];
  const float* cur_res     = (const float*)d_in[1];
  const int*   actions     = (const int*)d_in[2];
  const float* htm         = (const float*)d_in[3];
  const int*   pha         = (const int*)d_in[4];
  const float* W1          = (const float*)d_in[5];
  const float* b1          = (const float*)d_in[6];
  const float* gamma       = (const float*)d_in[7];
  const float* beta        = (const float*)d_in[8];
  const float* W2          = (const float*)d_in[9];
  const float* b2          = (const float*)d_in[10];
  const float* Wd          = (const float*)d_in[11];
  const float* bd          = (const float*)d_in[12];
  float* out = (float*)d_out;
  float* ws  = (float*)d_ws;

  prep_kernel<<<1, 256, 0, stream>>>(W2, Wd, b2, bd, ws);
  fused_kernel<<<NBLK, 256, 0, stream>>>(main_inputs, cur_res, actions, htm,
                                         pha, W1, b1, gamma, beta, ws, out,
                                         ws + WS_EP);
  ent_reduce<<<1, 256, 0, stream>>>(ws + WS_EP, out);
}